// Round 9
// baseline (208.530 us; speedup 1.0000x reference)
//
#include <hip/hip_runtime.h>
#include <hip/hip_bf16.h>

// GRNN tree transform v22 (r28: k_inner T14 async-stage split).
// r27 ledger: lvl11 45.6 + tailA 44.6 visible; ~105us invisible. k_inner is
// the worst gather case (128 random 256B rows from 33.6MB emb11 > L2) done
// in TWO serially-barriered phases. r28: issue all 8 uint4 gather loads
// (both phases) into registers in one burst after ch_s is ready -> ONE HBM
// latency exposure; drain to LDS at each phase boundary. Barriers, LDS,
// MFMA structure, numerics unchanged.
// r27's swapped u-MFMA in k_lvl11 and r26 prologue-hoisted tails retained.
//  1. k_prep0: wb cast + w_ub + ids_A + ids_B
//  2. k_lvl11: level-11 main (u via swapped MFMA; hoisted gathers)
//  3. k_inner j=10   4. k_tailA (levels 9..4)   5. k_tailB (levels 3..0)

#define NF 7
#define NH 128
#define XSTR 136      // k_inner xs stride (bf16)
#define XSTR3 392     // k_lvl11 xs stride: 384 + 8 pad
#define XS2 264       // tail xs stride (256 + 8 pad; 16B-aligned rows)
#define USTR 136      // u_all row stride

typedef __bf16 bf16;
typedef __bf16 bf16x4 __attribute__((ext_vector_type(4)));
typedef __bf16 bf16x8 __attribute__((ext_vector_type(8)));
typedef float floatx16 __attribute__((ext_vector_type(16)));
typedef float floatx2 __attribute__((ext_vector_type(2)));

__device__ __forceinline__ float ftanh(float x){
    // tanh(x) = 1 - 2/(exp2(x*2*log2e)+1); 5 VALU instrs, 2 transcendental.
    float e = __builtin_amdgcn_exp2f(x * 2.8853900817779268f);
    return fmaf(-2.0f, __builtin_amdgcn_rcpf(e + 1.0f), 1.0f);
}

__device__ __forceinline__ floatx2 pkfma(float c, floatx2 w, floatx2 a){
    floatx2 cc = {c, c};
    return __builtin_elementwise_fma(cc, w, a);   // -> v_pk_fma_f32
}

// ---------- launch 1: tiny prep ----------
// grid 197: [0,4) ids_A | 4: ids_B + w_ub | [5,197) wcast
__global__ __launch_bounds__(256) void k_prep0(
    const int2* __restrict__ children,
    const float* __restrict__ w_u, const float* __restrict__ b_u,
    const float* __restrict__ w_h,
    int* __restrict__ ids_A, int* __restrict__ ids_B,
    bf16* __restrict__ wb, bf16* __restrict__ w_ub)
{
    const int t = threadIdx.x;
    const int b = blockIdx.x;
    if (b < 4){
        int root = b * 256 + t;               // 0..1023
        int* base = ids_A + root * 128;
        const int2* ch4 = children + 960;
        const int2* ch5 = children + 1984;
        const int2* ch6 = children + 4032;
        const int2* ch7 = children + 8128;
        const int2* ch8 = children + 16320;
        const int2* ch9 = children + 32704;
        int l5[2], l6[4], l7[8], l8[16], l9[32];
        { int2 c = ch4[root]; l5[0] = c.x; l5[1] = c.y; }
        #pragma unroll
        for (int k = 0; k < 2; ++k){ int2 c = ch5[l5[k]]; l6[2*k] = c.x; l6[2*k+1] = c.y; }
        #pragma unroll
        for (int k = 0; k < 4; ++k){ int2 c = ch6[l6[k]]; l7[2*k] = c.x; l7[2*k+1] = c.y; }
        #pragma unroll
        for (int k = 0; k < 8; ++k){ int2 c = ch7[l7[k]]; l8[2*k] = c.x; l8[2*k+1] = c.y; }
        #pragma unroll
        for (int k = 0; k < 16; ++k){ int2 c = ch8[l8[k]]; l9[2*k] = c.x; l9[2*k+1] = c.y; }
        base[0] = root;
        base[1] = l5[0]; base[2] = l5[1];
        #pragma unroll
        for (int k = 0; k < 4; ++k)  base[3 + k]  = l6[k];
        #pragma unroll
        for (int k = 0; k < 8; ++k)  base[7 + k]  = l7[k];
        #pragma unroll
        for (int k = 0; k < 16; ++k) base[15 + k] = l8[k];
        #pragma unroll
        for (int k = 0; k < 32; ++k) base[31 + k] = l9[k];
        #pragma unroll
        for (int k = 0; k < 32; ++k){
            int2 c = ch9[l9[k]];
            base[63 + 2*k] = c.x; base[64 + 2*k] = c.y;
        }
    } else if (b == 4){
        if (t < 64){
            int root = t;
            int* base = ids_B + root * 32;
            const int2* ch0 = children;
            const int2* ch1 = children + 64;
            const int2* ch2 = children + 192;
            const int2* ch3 = children + 448;
            int l1[2], l2[4], l3[8];
            { int2 c = ch0[root]; l1[0] = c.x; l1[1] = c.y; }
            #pragma unroll
            for (int k = 0; k < 2; ++k){ int2 c = ch1[l1[k]]; l2[2*k] = c.x; l2[2*k+1] = c.y; }
            #pragma unroll
            for (int k = 0; k < 4; ++k){ int2 c = ch2[l2[k]]; l3[2*k] = c.x; l3[2*k+1] = c.y; }
            base[0] = root;
            base[1] = l1[0]; base[2] = l1[1];
            #pragma unroll
            for (int k = 0; k < 4; ++k) base[3 + k] = l2[k];
            #pragma unroll
            for (int k = 0; k < 8; ++k) base[7 + k] = l3[k];
            #pragma unroll
            for (int k = 0; k < 8; ++k){
                int2 c = ch3[l3[k]];
                base[15 + 2*k] = c.x; base[16 + 2*k] = c.y;
            }
        } else if (t < 192){
            int col = t - 64;                 // w_ub row: [128][16]
            union { uint4 u4[2]; bf16 h[16]; } row;
            #pragma unroll
            for (int f = 0; f < NF; ++f) row.h[f] = (bf16)w_u[col * NF + f];
            row.h[7] = (bf16)b_u[col];        // pairs with A's 1.0 at k=7
            #pragma unroll
            for (int k = 8; k < 16; ++k) row.h[k] = (bf16)0.0f;
            *(uint4*)&w_ub[col * 16]     = row.u4[0];
            *(uint4*)&w_ub[col * 16 + 8] = row.u4[1];
        }
    } else {
        int idx = (b - 5) * 256 + t;          // < 49152
        wb[idx] = (bf16)w_h[idx];
    }
}

// ---------- launch 2: level 11 main (64-node blocks, swapped u-MFMA) ----------
__global__ __launch_bounds__(256, 2) void k_lvl11(
    const float* __restrict__ contents, const int2* __restrict__ children,
    const bf16* __restrict__ w_ub, const bf16* __restrict__ wb,
    const float* __restrict__ b_h, bf16* __restrict__ emb11)
{
    __shared__ bf16 xs[64 * XSTR3];   // 50176 B
    __shared__ int chS[128];          // 512 B -> 50688 B total
    const int t = threadIdx.x;
    const int b = blockIdx.x;

    const int node0 = b * 64;
    const int2* ch11 = children + 131008;
    const float* cont11 = contents + (size_t)131008 * NF;
    const float* contL  = contents + (size_t)262080 * NF;

    if (t < 64){ int2 c = ch11[node0 + t]; chS[2*t] = c.x; chS[2*t + 1] = c.y; }

    const int lane = t & 63;
    const int ct = t >> 6;
    const int m = lane & 31;
    const int q = lane >> 5;
    const int colg = ct * 32 + m;
    const bf16x8 bu = *(const bf16x8*)(w_ub + (size_t)colg * 16 + q * 8);
    __syncthreads();   // chS ready

    // hoisted: all 6 tiles' contents gathers up-front (q=0 lanes) -> single
    // HBM latency exposure, fully pipelined.
    float rows[6][NF];
    if (q == 0){
        #pragma unroll
        for (int tile = 0; tile < 6; ++tile){
            const float* src;
            if (tile < 4) src = contL + (size_t)chS[tile * 32 + m] * NF;
            else          src = cont11 + (size_t)(node0 + (tile - 4) * 32 + m) * NF;
            #pragma unroll
            for (int f = 0; f < NF; ++f) rows[tile][f] = src[f];
        }
    }

    // u via SWAPPED MFMA: mfma(bu, a) = transpose of mfma(a, bu); lane m
    // holds node m's u across 16 dims in 4 runs of 4 -> packed b64 writes.
    #pragma unroll
    for (int tile = 0; tile < 6; ++tile){
        bf16x8 a = {bf16(0.f),bf16(0.f),bf16(0.f),bf16(0.f),
                    bf16(0.f),bf16(0.f),bf16(0.f),bf16(0.f)};
        if (q == 0){
            union { bf16x8 v; bf16 h[8]; } u8;
            #pragma unroll
            for (int f = 0; f < NF; ++f) u8.h[f] = (bf16)rows[tile][f];
            u8.h[7] = (bf16)1.0f;
            a = u8.v;
        }
        floatx16 acc = {0,0,0,0,0,0,0,0,0,0,0,0,0,0,0,0};
        acc = __builtin_amdgcn_mfma_f32_32x32x16_bf16(bu, a, acc, 0, 0, 0);
        bf16* dst;
        if (tile < 4){
            int c = tile * 32 + m;            // child index (fixed per lane)
            dst = &xs[(c >> 1) * XSTR3 + (c & 1) * 128 + ct * 32 + 4 * q];
        } else {
            dst = &xs[((tile - 4) * 32 + m) * XSTR3 + 256 + ct * 32 + 4 * q];
        }
        #pragma unroll
        for (int g2 = 0; g2 < 4; ++g2){
            bf16x4 pk4;
            pk4[0] = (bf16)ftanh(acc[4 * g2 + 0]);
            pk4[1] = (bf16)ftanh(acc[4 * g2 + 1]);
            pk4[2] = (bf16)ftanh(acc[4 * g2 + 2]);
            pk4[3] = (bf16)ftanh(acc[4 * g2 + 3]);
            *(bf16x4*)&dst[8 * g2] = pk4;     // 8B-aligned ds_write_b64
        }
    }
    __syncthreads();   // xs fully staged

    floatx16 acc0 = {0,0,0,0,0,0,0,0,0,0,0,0,0,0,0,0};
    floatx16 acc1 = {0,0,0,0,0,0,0,0,0,0,0,0,0,0,0,0};
    const bf16* bq = wb + (size_t)colg * 384 + q * 8;
    const bf16* xa = &xs[m * XSTR3 + q * 8];
    #pragma unroll
    for (int grp = 0; grp < 3; ++grp){
        bf16x8 bfr[8];
        #pragma unroll
        for (int kk = 0; kk < 8; ++kk)
            bfr[kk] = *(const bf16x8*)(bq + grp * 128 + kk * 16);
        #pragma unroll
        for (int kk = 0; kk < 8; ++kk){
            bf16x8 a0 = *(const bf16x8*)(xa + grp * 128 + kk * 16);
            bf16x8 a1 = *(const bf16x8*)(xa + grp * 128 + kk * 16 + 32 * XSTR3);
            acc0 = __builtin_amdgcn_mfma_f32_32x32x16_bf16(a0, bfr[kk], acc0, 0, 0, 0);
            acc1 = __builtin_amdgcn_mfma_f32_32x32x16_bf16(a1, bfr[kk], acc1, 0, 0, 0);
        }
    }

    const float bv = b_h[colg];
    #pragma unroll
    for (int nt = 0; nt < 2; ++nt){
        const floatx16* accp = nt ? &acc1 : &acc0;
        #pragma unroll
        for (int r = 0; r < 16; ++r){
            int row  = (r & 3) + 8 * (r >> 2) + 4 * q;
            int node = node0 + nt * 32 + row;
            emb11[(size_t)node * NH + colg] = (bf16)ftanh((*accp)[r] + bv);
        }
    }
}

// ---------- launch 3: k_inner j=10 (r28: hoisted gather burst) ----------
__global__ __launch_bounds__(256, 4) void k_inner(
    const int2* __restrict__ children, const float* __restrict__ contents,
    const float* __restrict__ w_u, const float* __restrict__ b_u,
    const bf16* __restrict__ wb, const float* __restrict__ b_h,
    const bf16* __restrict__ emb_next, bf16* __restrict__ out_b)
{
    __shared__ bf16 xs[64 * XSTR];
    __shared__ int2 ch_s[64];
    __shared__ float cs[64 * 8];
    const int t = threadIdx.x;
    const int block0 = blockIdx.x * 64;
    if (t < 64) ch_s[t] = children[block0 + t];
    if (t < 112){
        float4 v = ((const float4*)(contents + (size_t)block0 * NF))[t];
        int e = t * 4;
        float vv[4] = {v.x, v.y, v.z, v.w};
        #pragma unroll
        for (int r = 0; r < 4; ++r){ int ee = e + r; cs[(ee/7)*8 + (ee%7)] = vv[r]; }
    }
    const int cp = t & 63;
    const int quarter = t >> 6;
    floatx2 wu2[NF];
    {
        const float* w0 = w_u + (size_t)(2 * cp) * NF;
        #pragma unroll
        for (int f = 0; f < NF; ++f){ floatx2 w = {w0[f], w0[NF + f]}; wu2[f] = w; }
    }
    floatx2 bu2 = {b_u[2 * cp], b_u[2 * cp + 1]};
    const int lane = t & 63;
    const int ct = t >> 6;
    const int m = lane & 31;
    const int q = lane >> 5;
    floatx16 acc0 = {0,0,0,0,0,0,0,0,0,0,0,0,0,0,0,0};
    floatx16 acc1 = {0,0,0,0,0,0,0,0,0,0,0,0,0,0,0,0};
    const bf16* bq = wb + ((size_t)(ct * 32 + m) * 384 + q * 8);

    __syncthreads();   // ch_s + cs ready

    // T14: issue ALL 8 gather loads (both phases) in one burst -> one HBM
    // latency exposure. v0 consumed at phase 0, v1 at phase 1.
    uint4 v0[4], v1[4];
    #pragma unroll
    for (int r = 0; r < 4; ++r){
        int task = r * 256 + t;
        int i = task >> 4, part = task & 15;
        int2 c = ch_s[i];
        v0[r] = *(const uint4*)(emb_next + (size_t)c.x * NH + part * 8);
        v1[r] = *(const uint4*)(emb_next + (size_t)c.y * NH + part * 8);
    }

    #pragma unroll 1
    for (int p = 0; p < 3; ++p){
        if (p > 0) __syncthreads();   // previous phase's MFMA reads done
        if (p < 2){
            #pragma unroll
            for (int r = 0; r < 4; ++r){
                int task = r * 256 + t;
                int i = task >> 4, part = task & 15;
                *(uint4*)&xs[i * XSTR + part * 8] = (p == 0) ? v0[r] : v1[r];
            }
        } else {
            #pragma unroll 4
            for (int i = 0; i < 16; ++i){
                int node = quarter * 16 + i;
                float4 c0 = *(const float4*)&cs[node * 8];
                float4 c1 = *(const float4*)&cs[node * 8 + 4];
                floatx2 a = bu2;
                a = pkfma(c0.x, wu2[0], a);
                a = pkfma(c0.y, wu2[1], a);
                a = pkfma(c0.z, wu2[2], a);
                a = pkfma(c0.w, wu2[3], a);
                a = pkfma(c1.x, wu2[4], a);
                a = pkfma(c1.y, wu2[5], a);
                a = pkfma(c1.z, wu2[6], a);
                union { unsigned int u; bf16 h[2]; } pk;
                pk.h[0] = (bf16)ftanh(a[0]);
                pk.h[1] = (bf16)ftanh(a[1]);
                ((unsigned int*)xs)[node * (XSTR / 2) + cp] = pk.u;
            }
        }
        bf16x8 bfr[8];
        #pragma unroll
        for (int kk = 0; kk < 8; ++kk)
            bfr[kk] = *(const bf16x8*)(bq + p * 128 + kk * 16);
        __syncthreads();
        const bf16* xa = &xs[m * XSTR + q * 8];
        #pragma unroll
        for (int kk = 0; kk < 8; ++kk){
            bf16x8 a0 = *(const bf16x8*)(xa + kk * 16);
            bf16x8 a1 = *(const bf16x8*)(xa + kk * 16 + 32 * XSTR);
            acc0 = __builtin_amdgcn_mfma_f32_32x32x16_bf16(a0, bfr[kk], acc0, 0, 0, 0);
            acc1 = __builtin_amdgcn_mfma_f32_32x32x16_bf16(a1, bfr[kk], acc1, 0, 0, 0);
        }
    }
    const int colg = ct * 32 + m;
    const float bv = b_h[colg];
    #pragma unroll
    for (int nt = 0; nt < 2; ++nt){
        const floatx16* accp = nt ? &acc1 : &acc0;
        #pragma unroll
        for (int r = 0; r < 16; ++r){
            int row  = (r & 3) + 8 * (r >> 2) + 4 * q;
            int node = block0 + nt * 32 + row;
            out_b[(size_t)node * NH + colg] = (bf16)ftanh((*accp)[r] + bv);
        }
    }
}

// ---------- launch 4: k_tailA (prologue-hoisted globals) ----------
__global__ __launch_bounds__(256, 2) void k_tailA(
    const int* __restrict__ ids_A, const float* __restrict__ contents,
    const float* __restrict__ w_u, const float* __restrict__ b_u,
    const bf16* __restrict__ wb, const float* __restrict__ b_h,
    const bf16* __restrict__ emb10, bf16* __restrict__ emb4)
{
    __shared__ bf16 xs[32 * XS2];      // 16896 B (h_L|h_R only)
    __shared__ bf16 embL[32 * 136];    //  8704 B
    __shared__ bf16 u_all[63 * USTR];  // 17136 B (all 63 u-rows)
    __shared__ int ids[128];           //   512 B  -> 43248 B total
    const int t = threadIdx.x, root = blockIdx.x;
    const int ct = t >> 6, lane = t & 63, m = lane & 31, q = lane >> 5;
    const int cp = t & 63;
    const float bv = b_h[ct * 32 + m];
    if (t < 32) ((uint4*)ids)[t] = ((const uint4*)(ids_A + root * 128))[t];
    const bf16* bq = wb + ((size_t)(ct * 32 + m) * 384 + q * 8);

    floatx2 wu2[NF];
    {
        const float* w0 = w_u + (size_t)(2 * cp) * NF;
        #pragma unroll
        for (int f = 0; f < NF; ++f){ floatx2 w = {w0[f], w0[NF + f]}; wu2[f] = w; }
    }
    const floatx2 bu2 = {b_u[2 * cp], b_u[2 * cp + 1]};

    bf16x8 bfr[3][8];
    #pragma unroll
    for (int grp = 0; grp < 3; ++grp)
        #pragma unroll
        for (int kk = 0; kk < 8; ++kk)
            bfr[grp][kk] = *(const bf16x8*)(bq + grp * 128 + kk * 16);
    __syncthreads();   // ids ready

    // ---- prologue: ALL global loads, one pipelined burst ----
    #pragma unroll
    for (int r = 0; r < 4; ++r){
        int task = r * 256 + t;
        int i = task >> 5, half = (task >> 4) & 1, part = task & 15;
        uint4 v = *(const uint4*)(emb10 + (size_t)ids[63 + 2*i + half] * NH + part * 8);
        *(uint4*)&xs[i * XS2 + half * 128 + part * 8] = v;
    }
    #pragma unroll
    for (int r = 0; r < 16; ++r){
        int task = r * 256 + t;
        if (task < 4032){
            int j = task >> 6;                     // wave-uniform
            int k = 31 - __clz(j + 1);             // level: l = 4 + k
            size_t row = ((size_t)1024 << k) - 64 + ids[j];
            const float* src = contents + row * NF;
            floatx2 a = bu2;
            a = pkfma(src[0], wu2[0], a);
            a = pkfma(src[1], wu2[1], a);
            a = pkfma(src[2], wu2[2], a);
            a = pkfma(src[3], wu2[3], a);
            a = pkfma(src[4], wu2[4], a);
            a = pkfma(src[5], wu2[5], a);
            a = pkfma(src[6], wu2[6], a);
            union { unsigned int u; bf16 h[2]; } pk;
            pk.h[0] = (bf16)ftanh(a[0]);
            pk.h[1] = (bf16)ftanh(a[1]);
            *(unsigned int*)&u_all[j * USTR + 2 * cp] = pk.u;
        }
    }
    __syncthreads();   // xs + u_all ready

    #pragma unroll 1
    for (int l = 9; l >= 4; --l){
        const int n = 1 << (l - 4);
        if (l < 9){
            #pragma unroll
            for (int r = 0; r < 2; ++r){
                int task = r * 256 + t;
                if (task < n * 32){
                    int i = task >> 5, half = (task >> 4) & 1, part = task & 15;
                    *(uint4*)&xs[i * XS2 + half * 128 + part * 8] =
                        *(uint4*)&embL[(2*i + half) * 136 + part * 8];
                }
            }
            __syncthreads();
        }
        floatx16 accs[3];
        #pragma unroll
        for (int g = 0; g < 3; ++g) accs[g] = (floatx16){0,0,0,0,0,0,0,0,0,0,0,0,0,0,0,0};
        const bf16* xa  = &xs[m * XS2 + q * 8];
        const bf16* xau = &u_all[((n - 1) + m) * USTR + q * 8];
        #pragma unroll
        for (int g = 0; g < 2; ++g)
            #pragma unroll
            for (int kk = 0; kk < 8; ++kk){
                bf16x8 a0 = *(const bf16x8*)(xa + g * 128 + kk * 16);
                accs[g] = __builtin_amdgcn_mfma_f32_32x32x16_bf16(a0, bfr[g][kk], accs[g], 0, 0, 0);
            }
        #pragma unroll
        for (int kk = 0; kk < 8; ++kk){
            bf16x8 a0 = *(const bf16x8*)(xau + kk * 16);
            accs[2] = __builtin_amdgcn_mfma_f32_32x32x16_bf16(a0, bfr[2][kk], accs[2], 0, 0, 0);
        }
        floatx16 acc = accs[0] + accs[1] + accs[2];
        __syncthreads();   // xs/embL reads done
        #pragma unroll
        for (int r = 0; r < 16; ++r){
            int row = (r & 3) + 8 * (r >> 2) + 4 * q;
            if (row < n){
                float v = ftanh(acc[r] + bv);
                if (l > 4) embL[row * 136 + ct * 32 + m] = (bf16)v;
                else       emb4[(size_t)root * NH + ct * 32 + m] = (bf16)v;
            }
        }
        __syncthreads();   // embL visible for next stage
    }
}

// ---------- launch 5: k_tailB (prologue-hoisted globals) ----------
__global__ __launch_bounds__(256, 2) void k_tailB(
    const int* __restrict__ ids_B, const float* __restrict__ contents,
    const float* __restrict__ w_u, const float* __restrict__ b_u,
    const bf16* __restrict__ wb, const float* __restrict__ b_h,
    const bf16* __restrict__ emb4, float* __restrict__ out_f)
{
    __shared__ bf16 xs[8 * XS2];       // 4224 B
    __shared__ bf16 embL[8 * 136];     // 2176 B
    __shared__ bf16 u_all[16 * USTR];  // 4352 B (15 rows used, 1 pad for mask)
    __shared__ int ids[32];            //  128 B
    const int t = threadIdx.x, root = blockIdx.x;
    const int ct = t >> 6, lane = t & 63, m = lane & 31, q = lane >> 5;
    const int cp = t & 63;
    const float bv = b_h[ct * 32 + m];
    if (t < 8) ((uint4*)ids)[t] = ((const uint4*)(ids_B + root * 32))[t];
    const bf16* bq = wb + ((size_t)(ct * 32 + m) * 384 + q * 8);

    floatx2 wu2[NF];
    {
        const float* w0 = w_u + (size_t)(2 * cp) * NF;
        #pragma unroll
        for (int f = 0; f < NF; ++f){ floatx2 w = {w0[f], w0[NF + f]}; wu2[f] = w; }
    }
    const floatx2 bu2 = {b_u[2 * cp], b_u[2 * cp + 1]};

    bf16x8 bfr[3][8];
    #pragma unroll
    for (int grp = 0; grp < 3; ++grp)
        #pragma unroll
        for (int kk = 0; kk < 8; ++kk)
            bfr[grp][kk] = *(const bf16x8*)(bq + grp * 128 + kk * 16);
    __syncthreads();   // ids ready

    // ---- prologue: all global loads ----
    {   // level-3 children from emb4 (exactly 256 tasks)
        int i = t >> 5, half = (t >> 4) & 1, part = t & 15;
        uint4 v = *(const uint4*)(emb4 + (size_t)ids[15 + 2*i + half] * NH + part * 8);
        *(uint4*)&xs[i * XS2 + half * 128 + part * 8] = v;
    }
    #pragma unroll
    for (int r = 0; r < 4; ++r){
        int task = r * 256 + t;
        if (task < 960){
            int j = task >> 6;
            int k = 31 - __clz(j + 1);             // level l = k
            size_t row = ((size_t)64 << k) - 64 + ids[j];
            const float* src = contents + row * NF;
            floatx2 a = bu2;
            a = pkfma(src[0], wu2[0], a);
            a = pkfma(src[1], wu2[1], a);
            a = pkfma(src[2], wu2[2], a);
            a = pkfma(src[3], wu2[3], a);
            a = pkfma(src[4], wu2[4], a);
            a = pkfma(src[5], wu2[5], a);
            a = pkfma(src[6], wu2[6], a);
            union { unsigned int u; bf16 h[2]; } pk;
            pk.h[0] = (bf16)ftanh(a[0]);
            pk.h[1] = (bf16)ftanh(a[1]);
            *(unsigned int*)&u_all[j * USTR + 2 * cp] = pk.u;
        }
    }
    __syncthreads();

    #pragma unroll 1
    for (int l = 3; l >= 0; --l){
        const int n = 1 << l;
        if (l < 3){
            int task = t;
            if (task < n * 32){
                int i = task >> 5, half = (task >> 4) & 1, part = task & 15;
                *(uint4*)&xs[i * XS2 + half * 128 + part * 8] =
                    *(uint4*)&embL[(2*i + half) * 136 + part * 8];
            }
            __syncthreads();
        }
        floatx16 accs[3];
        #pragma unroll
        for (int g = 0; g < 3; ++g) accs[g] = (floatx16){0,0,0,0,0,0,0,0,0,0,0,0,0,0,0,0};
        const bf16* xa  = &xs[(m & 7) * XS2 + q * 8];
        const bf16* xau = &u_all[(((n - 1) + m) & 15) * USTR + q * 8];
        #pragma unroll
        for (int g = 0; g < 2; ++g)
            #pragma unroll
            for (int kk = 0; kk < 8; ++kk){
                bf16x8 a0 = *(const bf16x8*)(xa + g * 128 + kk * 16);
                accs[g] = __builtin_amdgcn_mfma_f32_32x32x16_bf16(a0, bfr[g][kk], accs[g], 0, 0, 0);
            }
        #pragma unroll
        for (int kk = 0; kk < 8; ++kk){
            bf16x8 a0 = *(const bf16x8*)(xau + kk * 16);
            accs[2] = __builtin_amdgcn_mfma_f32_32x32x16_bf16(a0, bfr[2][kk], accs[2], 0, 0, 0);
        }
        floatx16 acc = accs[0] + accs[1] + accs[2];
        __syncthreads();
        #pragma unroll
        for (int r = 0; r < 16; ++r){
            int row = (r & 3) + 8 * (r >> 2) + 4 * q;
            if (row < n){
                float v = ftanh(acc[r] + bv);
                if (l > 0) embL[row * 136 + ct * 32 + m] = (bf16)v;
                else       out_f[(size_t)root * NH + ct * 32 + m] = v;
            }
        }
        __syncthreads();
    }
}

// ---------- launcher ----------
extern "C" void kernel_launch(void* const* d_in, const int* in_sizes, int n_in,
                              void* d_out, int out_size, void* d_ws, size_t ws_size,
                              hipStream_t stream){
    const float* contents = (const float*)d_in[0];
    const int2*  children = (const int2*)d_in[1];
    const float* w_u      = (const float*)d_in[2];
    const float* b_u      = (const float*)d_in[3];
    const float* w_h      = (const float*)d_in[4];
    const float* b_h      = (const float*)d_in[5];
    float* outf = (float*)d_out;

    // ws: embA 16.8MB (emb10) | embB 33.6MB (emb11/emb4) | wb 96KB |
    //     ids_A 512KB | ids_B 8KB | w_ub 4KB
    bf16* embA    = (bf16*)d_ws;
    bf16* embB    = embA + (size_t)65536 * NH;
    bf16* wb      = embB + (size_t)131072 * NH;
    int*  ids_A   = (int*)(wb + (size_t)NH * 384);
    int*  ids_B   = ids_A + 1024 * 128;
    bf16* w_ub    = (bf16*)(ids_B + 64 * 32);

    hipLaunchKernelGGL(k_prep0, dim3(197), dim3(256), 0, stream,
                       children, w_u, b_u, w_h, ids_A, ids_B, wb, w_ub);
    hipLaunchKernelGGL(k_lvl11, dim3(2048), dim3(256), 0, stream,
                       contents, children, w_ub, wb, b_h, embB);
    hipLaunchKernelGGL(k_inner, dim3(1024), dim3(256), 0, stream,
                       children + 65472, contents + (size_t)65472 * NF,
                       w_u, b_u, wb, b_h, embB, embA);
    hipLaunchKernelGGL(k_tailA, dim3(1024), dim3(256), 0, stream,
                       ids_A, contents, w_u, b_u, wb, b_h, embA, embB);
    hipLaunchKernelGGL(k_tailB, dim3(64), dim3(256), 0, stream,
                       ids_B, contents, w_u, b_u, wb, b_h, embB, outf);
}

// Round 10
// 193.792 us; speedup vs baseline: 1.0761x; 1.0761x over previous
//
#include <hip/hip_runtime.h>
#include <hip/hip_bf16.h>

// GRNN tree transform v23 (r29).
// r28 post-mortem: k_inner's 8-uint4 register burst blew the (256,4)
// 128-VGPR cap -> scratch spill (VGPR_Count 48, Occ 0.5%, 134us). REVERTED
// k_inner to the r27 two-phase form. New change: k_tailA (256,2)->(256,3):
// latency-bound (HBM 3.7%, pipes <20%) with independent root-blocks; LDS
// 43.2KB fits 3 blocks/CU, VGPR 92 < 168 cap -> +50% co-resident blocks
// for cross-block latency overlap. No numerics change anywhere.
//  1. k_prep0: wb cast + w_ub + ids_A + ids_B
//  2. k_lvl11: level-11 main (u via swapped MFMA; hoisted gathers)
//  3. k_inner j=10   4. k_tailA (levels 9..4)   5. k_tailB (levels 3..0)

#define NF 7
#define NH 128
#define XSTR 136      // k_inner xs stride (bf16)
#define XSTR3 392     // k_lvl11 xs stride: 384 + 8 pad
#define XS2 264       // tail xs stride (256 + 8 pad; 16B-aligned rows)
#define USTR 136      // u_all row stride

typedef __bf16 bf16;
typedef __bf16 bf16x4 __attribute__((ext_vector_type(4)));
typedef __bf16 bf16x8 __attribute__((ext_vector_type(8)));
typedef float floatx16 __attribute__((ext_vector_type(16)));
typedef float floatx2 __attribute__((ext_vector_type(2)));

__device__ __forceinline__ float ftanh(float x){
    // tanh(x) = 1 - 2/(exp2(x*2*log2e)+1); 5 VALU instrs, 2 transcendental.
    float e = __builtin_amdgcn_exp2f(x * 2.8853900817779268f);
    return fmaf(-2.0f, __builtin_amdgcn_rcpf(e + 1.0f), 1.0f);
}

__device__ __forceinline__ floatx2 pkfma(float c, floatx2 w, floatx2 a){
    floatx2 cc = {c, c};
    return __builtin_elementwise_fma(cc, w, a);   // -> v_pk_fma_f32
}

// ---------- launch 1: tiny prep ----------
// grid 197: [0,4) ids_A | 4: ids_B + w_ub | [5,197) wcast
__global__ __launch_bounds__(256) void k_prep0(
    const int2* __restrict__ children,
    const float* __restrict__ w_u, const float* __restrict__ b_u,
    const float* __restrict__ w_h,
    int* __restrict__ ids_A, int* __restrict__ ids_B,
    bf16* __restrict__ wb, bf16* __restrict__ w_ub)
{
    const int t = threadIdx.x;
    const int b = blockIdx.x;
    if (b < 4){
        int root = b * 256 + t;               // 0..1023
        int* base = ids_A + root * 128;
        const int2* ch4 = children + 960;
        const int2* ch5 = children + 1984;
        const int2* ch6 = children + 4032;
        const int2* ch7 = children + 8128;
        const int2* ch8 = children + 16320;
        const int2* ch9 = children + 32704;
        int l5[2], l6[4], l7[8], l8[16], l9[32];
        { int2 c = ch4[root]; l5[0] = c.x; l5[1] = c.y; }
        #pragma unroll
        for (int k = 0; k < 2; ++k){ int2 c = ch5[l5[k]]; l6[2*k] = c.x; l6[2*k+1] = c.y; }
        #pragma unroll
        for (int k = 0; k < 4; ++k){ int2 c = ch6[l6[k]]; l7[2*k] = c.x; l7[2*k+1] = c.y; }
        #pragma unroll
        for (int k = 0; k < 8; ++k){ int2 c = ch7[l7[k]]; l8[2*k] = c.x; l8[2*k+1] = c.y; }
        #pragma unroll
        for (int k = 0; k < 16; ++k){ int2 c = ch8[l8[k]]; l9[2*k] = c.x; l9[2*k+1] = c.y; }
        base[0] = root;
        base[1] = l5[0]; base[2] = l5[1];
        #pragma unroll
        for (int k = 0; k < 4; ++k)  base[3 + k]  = l6[k];
        #pragma unroll
        for (int k = 0; k < 8; ++k)  base[7 + k]  = l7[k];
        #pragma unroll
        for (int k = 0; k < 16; ++k) base[15 + k] = l8[k];
        #pragma unroll
        for (int k = 0; k < 32; ++k) base[31 + k] = l9[k];
        #pragma unroll
        for (int k = 0; k < 32; ++k){
            int2 c = ch9[l9[k]];
            base[63 + 2*k] = c.x; base[64 + 2*k] = c.y;
        }
    } else if (b == 4){
        if (t < 64){
            int root = t;
            int* base = ids_B + root * 32;
            const int2* ch0 = children;
            const int2* ch1 = children + 64;
            const int2* ch2 = children + 192;
            const int2* ch3 = children + 448;
            int l1[2], l2[4], l3[8];
            { int2 c = ch0[root]; l1[0] = c.x; l1[1] = c.y; }
            #pragma unroll
            for (int k = 0; k < 2; ++k){ int2 c = ch1[l1[k]]; l2[2*k] = c.x; l2[2*k+1] = c.y; }
            #pragma unroll
            for (int k = 0; k < 4; ++k){ int2 c = ch2[l2[k]]; l3[2*k] = c.x; l3[2*k+1] = c.y; }
            base[0] = root;
            base[1] = l1[0]; base[2] = l1[1];
            #pragma unroll
            for (int k = 0; k < 4; ++k) base[3 + k] = l2[k];
            #pragma unroll
            for (int k = 0; k < 8; ++k) base[7 + k] = l3[k];
            #pragma unroll
            for (int k = 0; k < 8; ++k){
                int2 c = ch3[l3[k]];
                base[15 + 2*k] = c.x; base[16 + 2*k] = c.y;
            }
        } else if (t < 192){
            int col = t - 64;                 // w_ub row: [128][16]
            union { uint4 u4[2]; bf16 h[16]; } row;
            #pragma unroll
            for (int f = 0; f < NF; ++f) row.h[f] = (bf16)w_u[col * NF + f];
            row.h[7] = (bf16)b_u[col];        // pairs with A's 1.0 at k=7
            #pragma unroll
            for (int k = 8; k < 16; ++k) row.h[k] = (bf16)0.0f;
            *(uint4*)&w_ub[col * 16]     = row.u4[0];
            *(uint4*)&w_ub[col * 16 + 8] = row.u4[1];
        }
    } else {
        int idx = (b - 5) * 256 + t;          // < 49152
        wb[idx] = (bf16)w_h[idx];
    }
}

// ---------- launch 2: level 11 main (64-node blocks, swapped u-MFMA) ----------
__global__ __launch_bounds__(256, 2) void k_lvl11(
    const float* __restrict__ contents, const int2* __restrict__ children,
    const bf16* __restrict__ w_ub, const bf16* __restrict__ wb,
    const float* __restrict__ b_h, bf16* __restrict__ emb11)
{
    __shared__ bf16 xs[64 * XSTR3];   // 50176 B
    __shared__ int chS[128];          // 512 B -> 50688 B total
    const int t = threadIdx.x;
    const int b = blockIdx.x;

    const int node0 = b * 64;
    const int2* ch11 = children + 131008;
    const float* cont11 = contents + (size_t)131008 * NF;
    const float* contL  = contents + (size_t)262080 * NF;

    if (t < 64){ int2 c = ch11[node0 + t]; chS[2*t] = c.x; chS[2*t + 1] = c.y; }

    const int lane = t & 63;
    const int ct = t >> 6;
    const int m = lane & 31;
    const int q = lane >> 5;
    const int colg = ct * 32 + m;
    const bf16x8 bu = *(const bf16x8*)(w_ub + (size_t)colg * 16 + q * 8);
    __syncthreads();   // chS ready

    // hoisted: all 6 tiles' contents gathers up-front (q=0 lanes) -> single
    // HBM latency exposure, fully pipelined.
    float rows[6][NF];
    if (q == 0){
        #pragma unroll
        for (int tile = 0; tile < 6; ++tile){
            const float* src;
            if (tile < 4) src = contL + (size_t)chS[tile * 32 + m] * NF;
            else          src = cont11 + (size_t)(node0 + (tile - 4) * 32 + m) * NF;
            #pragma unroll
            for (int f = 0; f < NF; ++f) rows[tile][f] = src[f];
        }
    }

    // u via SWAPPED MFMA: mfma(bu, a) = transpose of mfma(a, bu); lane m
    // holds node m's u across 16 dims in 4 runs of 4 -> packed b64 writes.
    #pragma unroll
    for (int tile = 0; tile < 6; ++tile){
        bf16x8 a = {bf16(0.f),bf16(0.f),bf16(0.f),bf16(0.f),
                    bf16(0.f),bf16(0.f),bf16(0.f),bf16(0.f)};
        if (q == 0){
            union { bf16x8 v; bf16 h[8]; } u8;
            #pragma unroll
            for (int f = 0; f < NF; ++f) u8.h[f] = (bf16)rows[tile][f];
            u8.h[7] = (bf16)1.0f;
            a = u8.v;
        }
        floatx16 acc = {0,0,0,0,0,0,0,0,0,0,0,0,0,0,0,0};
        acc = __builtin_amdgcn_mfma_f32_32x32x16_bf16(bu, a, acc, 0, 0, 0);
        bf16* dst;
        if (tile < 4){
            int c = tile * 32 + m;            // child index (fixed per lane)
            dst = &xs[(c >> 1) * XSTR3 + (c & 1) * 128 + ct * 32 + 4 * q];
        } else {
            dst = &xs[((tile - 4) * 32 + m) * XSTR3 + 256 + ct * 32 + 4 * q];
        }
        #pragma unroll
        for (int g2 = 0; g2 < 4; ++g2){
            bf16x4 pk4;
            pk4[0] = (bf16)ftanh(acc[4 * g2 + 0]);
            pk4[1] = (bf16)ftanh(acc[4 * g2 + 1]);
            pk4[2] = (bf16)ftanh(acc[4 * g2 + 2]);
            pk4[3] = (bf16)ftanh(acc[4 * g2 + 3]);
            *(bf16x4*)&dst[8 * g2] = pk4;     // 8B-aligned ds_write_b64
        }
    }
    __syncthreads();   // xs fully staged

    floatx16 acc0 = {0,0,0,0,0,0,0,0,0,0,0,0,0,0,0,0};
    floatx16 acc1 = {0,0,0,0,0,0,0,0,0,0,0,0,0,0,0,0};
    const bf16* bq = wb + (size_t)colg * 384 + q * 8;
    const bf16* xa = &xs[m * XSTR3 + q * 8];
    #pragma unroll
    for (int grp = 0; grp < 3; ++grp){
        bf16x8 bfr[8];
        #pragma unroll
        for (int kk = 0; kk < 8; ++kk)
            bfr[kk] = *(const bf16x8*)(bq + grp * 128 + kk * 16);
        #pragma unroll
        for (int kk = 0; kk < 8; ++kk){
            bf16x8 a0 = *(const bf16x8*)(xa + grp * 128 + kk * 16);
            bf16x8 a1 = *(const bf16x8*)(xa + grp * 128 + kk * 16 + 32 * XSTR3);
            acc0 = __builtin_amdgcn_mfma_f32_32x32x16_bf16(a0, bfr[kk], acc0, 0, 0, 0);
            acc1 = __builtin_amdgcn_mfma_f32_32x32x16_bf16(a1, bfr[kk], acc1, 0, 0, 0);
        }
    }

    const float bv = b_h[colg];
    #pragma unroll
    for (int nt = 0; nt < 2; ++nt){
        const floatx16* accp = nt ? &acc1 : &acc0;
        #pragma unroll
        for (int r = 0; r < 16; ++r){
            int row  = (r & 3) + 8 * (r >> 2) + 4 * q;
            int node = node0 + nt * 32 + row;
            emb11[(size_t)node * NH + colg] = (bf16)ftanh((*accp)[r] + bv);
        }
    }
}

// ---------- launch 3: k_inner j=10 (r27-proven two-phase form) ----------
__global__ __launch_bounds__(256, 4) void k_inner(
    const int2* __restrict__ children, const float* __restrict__ contents,
    const float* __restrict__ w_u, const float* __restrict__ b_u,
    const bf16* __restrict__ wb, const float* __restrict__ b_h,
    const bf16* __restrict__ emb_next, bf16* __restrict__ out_b)
{
    __shared__ bf16 xs[64 * XSTR];
    __shared__ int2 ch_s[64];
    __shared__ float cs[64 * 8];
    const int t = threadIdx.x;
    const int block0 = blockIdx.x * 64;
    if (t < 64) ch_s[t] = children[block0 + t];
    if (t < 112){
        float4 v = ((const float4*)(contents + (size_t)block0 * NF))[t];
        int e = t * 4;
        float vv[4] = {v.x, v.y, v.z, v.w};
        #pragma unroll
        for (int r = 0; r < 4; ++r){ int ee = e + r; cs[(ee/7)*8 + (ee%7)] = vv[r]; }
    }
    const int cp = t & 63;
    const int quarter = t >> 6;
    floatx2 wu2[NF];
    {
        const float* w0 = w_u + (size_t)(2 * cp) * NF;
        #pragma unroll
        for (int f = 0; f < NF; ++f){ floatx2 w = {w0[f], w0[NF + f]}; wu2[f] = w; }
    }
    floatx2 bu2 = {b_u[2 * cp], b_u[2 * cp + 1]};
    const int lane = t & 63;
    const int ct = t >> 6;
    const int m = lane & 31;
    const int q = lane >> 5;
    floatx16 acc0 = {0,0,0,0,0,0,0,0,0,0,0,0,0,0,0,0};
    floatx16 acc1 = {0,0,0,0,0,0,0,0,0,0,0,0,0,0,0,0};
    const bf16* bq = wb + ((size_t)(ct * 32 + m) * 384 + q * 8);
    #pragma unroll 1
    for (int p = 0; p < 3; ++p){
        __syncthreads();
        if (p < 2){
            #pragma unroll
            for (int r = 0; r < 4; ++r){
                int task = r * 256 + t;
                int i = task >> 4, part = task & 15;
                int row = (p == 0) ? ch_s[i].x : ch_s[i].y;
                uint4 v = *(const uint4*)(emb_next + (size_t)row * NH + part * 8);
                *(uint4*)&xs[i * XSTR + part * 8] = v;
            }
        } else {
            #pragma unroll 4
            for (int i = 0; i < 16; ++i){
                int node = quarter * 16 + i;
                float4 c0 = *(const float4*)&cs[node * 8];
                float4 c1 = *(const float4*)&cs[node * 8 + 4];
                floatx2 a = bu2;
                a = pkfma(c0.x, wu2[0], a);
                a = pkfma(c0.y, wu2[1], a);
                a = pkfma(c0.z, wu2[2], a);
                a = pkfma(c0.w, wu2[3], a);
                a = pkfma(c1.x, wu2[4], a);
                a = pkfma(c1.y, wu2[5], a);
                a = pkfma(c1.z, wu2[6], a);
                union { unsigned int u; bf16 h[2]; } pk;
                pk.h[0] = (bf16)ftanh(a[0]);
                pk.h[1] = (bf16)ftanh(a[1]);
                ((unsigned int*)xs)[node * (XSTR / 2) + cp] = pk.u;
            }
        }
        bf16x8 bfr[8];
        #pragma unroll
        for (int kk = 0; kk < 8; ++kk)
            bfr[kk] = *(const bf16x8*)(bq + p * 128 + kk * 16);
        __syncthreads();
        const bf16* xa = &xs[m * XSTR + q * 8];
        #pragma unroll
        for (int kk = 0; kk < 8; ++kk){
            bf16x8 a0 = *(const bf16x8*)(xa + kk * 16);
            bf16x8 a1 = *(const bf16x8*)(xa + kk * 16 + 32 * XSTR);
            acc0 = __builtin_amdgcn_mfma_f32_32x32x16_bf16(a0, bfr[kk], acc0, 0, 0, 0);
            acc1 = __builtin_amdgcn_mfma_f32_32x32x16_bf16(a1, bfr[kk], acc1, 0, 0, 0);
        }
    }
    const int colg = ct * 32 + m;
    const float bv = b_h[colg];
    #pragma unroll
    for (int nt = 0; nt < 2; ++nt){
        const floatx16* accp = nt ? &acc1 : &acc0;
        #pragma unroll
        for (int r = 0; r < 16; ++r){
            int row  = (r & 3) + 8 * (r >> 2) + 4 * q;
            int node = block0 + nt * 32 + row;
            out_b[(size_t)node * NH + colg] = (bf16)ftanh((*accp)[r] + bv);
        }
    }
}

// ---------- launch 4: k_tailA (r29: (256,3) for TLP latency hiding) ----------
__global__ __launch_bounds__(256, 3) void k_tailA(
    const int* __restrict__ ids_A, const float* __restrict__ contents,
    const float* __restrict__ w_u, const float* __restrict__ b_u,
    const bf16* __restrict__ wb, const float* __restrict__ b_h,
    const bf16* __restrict__ emb10, bf16* __restrict__ emb4)
{
    __shared__ bf16 xs[32 * XS2];      // 16896 B (h_L|h_R only)
    __shared__ bf16 embL[32 * 136];    //  8704 B
    __shared__ bf16 u_all[63 * USTR];  // 17136 B (all 63 u-rows)
    __shared__ int ids[128];           //   512 B  -> 43248 B total, 3 blocks/CU
    const int t = threadIdx.x, root = blockIdx.x;
    const int ct = t >> 6, lane = t & 63, m = lane & 31, q = lane >> 5;
    const int cp = t & 63;
    const float bv = b_h[ct * 32 + m];
    if (t < 32) ((uint4*)ids)[t] = ((const uint4*)(ids_A + root * 128))[t];
    const bf16* bq = wb + ((size_t)(ct * 32 + m) * 384 + q * 8);

    floatx2 wu2[NF];
    {
        const float* w0 = w_u + (size_t)(2 * cp) * NF;
        #pragma unroll
        for (int f = 0; f < NF; ++f){ floatx2 w = {w0[f], w0[NF + f]}; wu2[f] = w; }
    }
    const floatx2 bu2 = {b_u[2 * cp], b_u[2 * cp + 1]};

    bf16x8 bfr[3][8];
    #pragma unroll
    for (int grp = 0; grp < 3; ++grp)
        #pragma unroll
        for (int kk = 0; kk < 8; ++kk)
            bfr[grp][kk] = *(const bf16x8*)(bq + grp * 128 + kk * 16);
    __syncthreads();   // ids ready

    // ---- prologue: ALL global loads, one pipelined burst ----
    #pragma unroll
    for (int r = 0; r < 4; ++r){
        int task = r * 256 + t;
        int i = task >> 5, half = (task >> 4) & 1, part = task & 15;
        uint4 v = *(const uint4*)(emb10 + (size_t)ids[63 + 2*i + half] * NH + part * 8);
        *(uint4*)&xs[i * XS2 + half * 128 + part * 8] = v;
    }
    #pragma unroll
    for (int r = 0; r < 16; ++r){
        int task = r * 256 + t;
        if (task < 4032){
            int j = task >> 6;                     // wave-uniform
            int k = 31 - __clz(j + 1);             // level: l = 4 + k
            size_t row = ((size_t)1024 << k) - 64 + ids[j];
            const float* src = contents + row * NF;
            floatx2 a = bu2;
            a = pkfma(src[0], wu2[0], a);
            a = pkfma(src[1], wu2[1], a);
            a = pkfma(src[2], wu2[2], a);
            a = pkfma(src[3], wu2[3], a);
            a = pkfma(src[4], wu2[4], a);
            a = pkfma(src[5], wu2[5], a);
            a = pkfma(src[6], wu2[6], a);
            union { unsigned int u; bf16 h[2]; } pk;
            pk.h[0] = (bf16)ftanh(a[0]);
            pk.h[1] = (bf16)ftanh(a[1]);
            *(unsigned int*)&u_all[j * USTR + 2 * cp] = pk.u;
        }
    }
    __syncthreads();   // xs + u_all ready

    #pragma unroll 1
    for (int l = 9; l >= 4; --l){
        const int n = 1 << (l - 4);
        if (l < 9){
            #pragma unroll
            for (int r = 0; r < 2; ++r){
                int task = r * 256 + t;
                if (task < n * 32){
                    int i = task >> 5, half = (task >> 4) & 1, part = task & 15;
                    *(uint4*)&xs[i * XS2 + half * 128 + part * 8] =
                        *(uint4*)&embL[(2*i + half) * 136 + part * 8];
                }
            }
            __syncthreads();
        }
        floatx16 accs[3];
        #pragma unroll
        for (int g = 0; g < 3; ++g) accs[g] = (floatx16){0,0,0,0,0,0,0,0,0,0,0,0,0,0,0,0};
        const bf16* xa  = &xs[m * XS2 + q * 8];
        const bf16* xau = &u_all[((n - 1) + m) * USTR + q * 8];
        #pragma unroll
        for (int g = 0; g < 2; ++g)
            #pragma unroll
            for (int kk = 0; kk < 8; ++kk){
                bf16x8 a0 = *(const bf16x8*)(xa + g * 128 + kk * 16);
                accs[g] = __builtin_amdgcn_mfma_f32_32x32x16_bf16(a0, bfr[g][kk], accs[g], 0, 0, 0);
            }
        #pragma unroll
        for (int kk = 0; kk < 8; ++kk){
            bf16x8 a0 = *(const bf16x8*)(xau + kk * 16);
            accs[2] = __builtin_amdgcn_mfma_f32_32x32x16_bf16(a0, bfr[2][kk], accs[2], 0, 0, 0);
        }
        floatx16 acc = accs[0] + accs[1] + accs[2];
        __syncthreads();   // xs/embL reads done
        #pragma unroll
        for (int r = 0; r < 16; ++r){
            int row = (r & 3) + 8 * (r >> 2) + 4 * q;
            if (row < n){
                float v = ftanh(acc[r] + bv);
                if (l > 4) embL[row * 136 + ct * 32 + m] = (bf16)v;
                else       emb4[(size_t)root * NH + ct * 32 + m] = (bf16)v;
            }
        }
        __syncthreads();   // embL visible for next stage
    }
}

// ---------- launch 5: k_tailB (prologue-hoisted globals) ----------
__global__ __launch_bounds__(256, 2) void k_tailB(
    const int* __restrict__ ids_B, const float* __restrict__ contents,
    const float* __restrict__ w_u, const float* __restrict__ b_u,
    const bf16* __restrict__ wb, const float* __restrict__ b_h,
    const bf16* __restrict__ emb4, float* __restrict__ out_f)
{
    __shared__ bf16 xs[8 * XS2];       // 4224 B
    __shared__ bf16 embL[8 * 136];     // 2176 B
    __shared__ bf16 u_all[16 * USTR];  // 4352 B (15 rows used, 1 pad for mask)
    __shared__ int ids[32];            //  128 B
    const int t = threadIdx.x, root = blockIdx.x;
    const int ct = t >> 6, lane = t & 63, m = lane & 31, q = lane >> 5;
    const int cp = t & 63;
    const float bv = b_h[ct * 32 + m];
    if (t < 8) ((uint4*)ids)[t] = ((const uint4*)(ids_B + root * 32))[t];
    const bf16* bq = wb + ((size_t)(ct * 32 + m) * 384 + q * 8);

    floatx2 wu2[NF];
    {
        const float* w0 = w_u + (size_t)(2 * cp) * NF;
        #pragma unroll
        for (int f = 0; f < NF; ++f){ floatx2 w = {w0[f], w0[NF + f]}; wu2[f] = w; }
    }
    const floatx2 bu2 = {b_u[2 * cp], b_u[2 * cp + 1]};

    bf16x8 bfr[3][8];
    #pragma unroll
    for (int grp = 0; grp < 3; ++grp)
        #pragma unroll
        for (int kk = 0; kk < 8; ++kk)
            bfr[grp][kk] = *(const bf16x8*)(bq + grp * 128 + kk * 16);
    __syncthreads();   // ids ready

    // ---- prologue: all global loads ----
    {   // level-3 children from emb4 (exactly 256 tasks)
        int i = t >> 5, half = (t >> 4) & 1, part = t & 15;
        uint4 v = *(const uint4*)(emb4 + (size_t)ids[15 + 2*i + half] * NH + part * 8);
        *(uint4*)&xs[i * XS2 + half * 128 + part * 8] = v;
    }
    #pragma unroll
    for (int r = 0; r < 4; ++r){
        int task = r * 256 + t;
        if (task < 960){
            int j = task >> 6;
            int k = 31 - __clz(j + 1);             // level l = k
            size_t row = ((size_t)64 << k) - 64 + ids[j];
            const float* src = contents + row * NF;
            floatx2 a = bu2;
            a = pkfma(src[0], wu2[0], a);
            a = pkfma(src[1], wu2[1], a);
            a = pkfma(src[2], wu2[2], a);
            a = pkfma(src[3], wu2[3], a);
            a = pkfma(src[4], wu2[4], a);
            a = pkfma(src[5], wu2[5], a);
            a = pkfma(src[6], wu2[6], a);
            union { unsigned int u; bf16 h[2]; } pk;
            pk.h[0] = (bf16)ftanh(a[0]);
            pk.h[1] = (bf16)ftanh(a[1]);
            *(unsigned int*)&u_all[j * USTR + 2 * cp] = pk.u;
        }
    }
    __syncthreads();

    #pragma unroll 1
    for (int l = 3; l >= 0; --l){
        const int n = 1 << l;
        if (l < 3){
            int task = t;
            if (task < n * 32){
                int i = task >> 5, half = (task >> 4) & 1, part = task & 15;
                *(uint4*)&xs[i * XS2 + half * 128 + part * 8] =
                    *(uint4*)&embL[(2*i + half) * 136 + part * 8];
            }
            __syncthreads();
        }
        floatx16 accs[3];
        #pragma unroll
        for (int g = 0; g < 3; ++g) accs[g] = (floatx16){0,0,0,0,0,0,0,0,0,0,0,0,0,0,0,0};
        const bf16* xa  = &xs[(m & 7) * XS2 + q * 8];
        const bf16* xau = &u_all[(((n - 1) + m) & 15) * USTR + q * 8];
        #pragma unroll
        for (int g = 0; g < 2; ++g)
            #pragma unroll
            for (int kk = 0; kk < 8; ++kk){
                bf16x8 a0 = *(const bf16x8*)(xa + g * 128 + kk * 16);
                accs[g] = __builtin_amdgcn_mfma_f32_32x32x16_bf16(a0, bfr[g][kk], accs[g], 0, 0, 0);
            }
        #pragma unroll
        for (int kk = 0; kk < 8; ++kk){
            bf16x8 a0 = *(const bf16x8*)(xau + kk * 16);
            accs[2] = __builtin_amdgcn_mfma_f32_32x32x16_bf16(a0, bfr[2][kk], accs[2], 0, 0, 0);
        }
        floatx16 acc = accs[0] + accs[1] + accs[2];
        __syncthreads();
        #pragma unroll
        for (int r = 0; r < 16; ++r){
            int row = (r & 3) + 8 * (r >> 2) + 4 * q;
            if (row < n){
                float v = ftanh(acc[r] + bv);
                if (l > 0) embL[row * 136 + ct * 32 + m] = (bf16)v;
                else       out_f[(size_t)root * NH + ct * 32 + m] = v;
            }
        }
        __syncthreads();
    }
}

// ---------- launcher ----------
extern "C" void kernel_launch(void* const* d_in, const int* in_sizes, int n_in,
                              void* d_out, int out_size, void* d_ws, size_t ws_size,
                              hipStream_t stream){
    const float* contents = (const float*)d_in[0];
    const int2*  children = (const int2*)d_in[1];
    const float* w_u      = (const float*)d_in[2];
    const float* b_u      = (const float*)d_in[3];
    const float* w_h      = (const float*)d_in[4];
    const float* b_h      = (const float*)d_in[5];
    float* outf = (float*)d_out;

    // ws: embA 16.8MB (emb10) | embB 33.6MB (emb11/emb4) | wb 96KB |
    //     ids_A 512KB | ids_B 8KB | w_ub 4KB
    bf16* embA    = (bf16*)d_ws;
    bf16* embB    = embA + (size_t)65536 * NH;
    bf16* wb      = embB + (size_t)131072 * NH;
    int*  ids_A   = (int*)(wb + (size_t)NH * 384);
    int*  ids_B   = ids_A + 1024 * 128;
    bf16* w_ub    = (bf16*)(ids_B + 64 * 32);

    hipLaunchKernelGGL(k_prep0, dim3(197), dim3(256), 0, stream,
                       children, w_u, b_u, w_h, ids_A, ids_B, wb, w_ub);
    hipLaunchKernelGGL(k_lvl11, dim3(2048), dim3(256), 0, stream,
                       contents, children, w_ub, wb, b_h, embB);
    hipLaunchKernelGGL(k_inner, dim3(1024), dim3(256), 0, stream,
                       children + 65472, contents + (size_t)65472 * NF,
                       w_u, b_u, wb, b_h, embB, embA);
    hipLaunchKernelGGL(k_tailA, dim3(1024), dim3(256), 0, stream,
                       ids_A, contents, w_u, b_u, wb, b_h, embA, embB);
    hipLaunchKernelGGL(k_tailB, dim3(64), dim3(256), 0, stream,
                       ids_B, contents, w_u, b_u, wb, b_h, embB, outf);
}